// Round 6
// baseline (267.372 us; speedup 1.0000x reference)
//
#include <hip/hip_runtime.h>
#include <math.h>

#define N_BINS 15
#define NSLOTS (3 * N_BINS)   // 45 accumulators; ws[45] = completion counter

typedef float fvec4 __attribute__((ext_vector_type(4)));  // native clang vector:
// __builtin_nontemporal_load needs scalar/native-vector, not HIP_vector_type.

// One wave (64 lanes) per row, grid-stride over rows, software-prefetched,
// NONTEMPORAL logits loads (pure 1.05 GB stream, zero reuse -> don't retain
// in L2/L3; measured +7%, R5). Per-block bin sums in LDS -> 45 global atomics
// per block. Epilogue fused via last-block-done: the final block to increment
// ws[45] computes the 31 outputs (saves the third dispatch).
__global__ __launch_bounds__(256) void ece_main(const float* __restrict__ logits,
                                                const int* __restrict__ labels,
                                                float* __restrict__ gbins, // ws: [45 sums][1 counter]
                                                float* __restrict__ out,   // [31]
                                                int N, int C, float invN) {
    __shared__ float sb[NSLOTS];
    __shared__ unsigned sLast;
    const int tid = threadIdx.x;
    if (tid < NSLOTS) sb[tid] = 0.0f;
    __syncthreads();

    const int lane = tid & 63;
    const int wid  = tid >> 6;
    const int wavesPerBlock = blockDim.x >> 6;
    const int wavesTotal = gridDim.x * wavesPerBlock;
    const int C4 = C >> 2;  // 250 for C=1000

    int row = blockIdx.x * wavesPerBlock + wid;

    fvec4 v[4];
    const fvec4 ninf = (fvec4)(-INFINITY);
    if (row < N) {
        const fvec4* rp = (const fvec4*)(logits + (size_t)row * C);
        #pragma unroll
        for (int c = 0; c < 4; ++c) {
            int f4i = c * 64 + lane;
            v[c] = (f4i < C4) ? __builtin_nontemporal_load(&rp[f4i]) : ninf;
        }
    }

    for (; row < N; row += wavesTotal) {
        int lbl = labels[row];

        // prefetch next row while we reduce this one
        int nrow = row + wavesTotal;
        fvec4 vn[4];
        if (nrow < N) {
            const fvec4* np = (const fvec4*)(logits + (size_t)nrow * C);
            #pragma unroll
            for (int c = 0; c < 4; ++c) {
                int f4i = c * 64 + lane;
                vn[c] = (f4i < C4) ? __builtin_nontemporal_load(&np[f4i]) : ninf;
            }
        } else {
            #pragma unroll
            for (int c = 0; c < 4; ++c) vn[c] = ninf;
        }

        // per-lane max + first-occurrence argmax (ascending scan, strict >)
        float m = -INFINITY;
        int   mi = 0x7fffffff;
        #pragma unroll
        for (int c = 0; c < 4; ++c) {
            int base = (c * 64 + lane) * 4;
            #pragma unroll
            for (int j = 0; j < 4; ++j) {
                float e = v[c][j];
                if (e > m) { m = e; mi = base + j; }
            }
        }
        // wave reduce: max, tie-break to smallest index
        #pragma unroll
        for (int off = 1; off < 64; off <<= 1) {
            float om = __shfl_xor(m, off, 64);
            int   oi = __shfl_xor(mi, off, 64);
            if (om > m || (om == m && oi < mi)) { m = om; mi = oi; }
        }

        // sum of exp(x - max); -inf fill lanes contribute exp(-inf)=0
        float s = 0.0f;
        #pragma unroll
        for (int c = 0; c < 4; ++c) {
            #pragma unroll
            for (int j = 0; j < 4; ++j) s += __expf(v[c][j] - m);
        }
        #pragma unroll
        for (int off = 1; off < 64; off <<= 1) s += __shfl_xor(s, off, 64);

        if (lane == 0) {
            float conf = 1.0f / s;                        // exp(max-max)/Z = 1/Z
            int bin = (int)ceilf(conf * (float)N_BINS) - 1;
            bin = bin < 0 ? 0 : (bin > N_BINS - 1 ? N_BINS - 1 : bin);
            float acc = (mi == lbl) ? 1.0f : 0.0f;
            atomicAdd(&sb[bin], 1.0f);
            atomicAdd(&sb[N_BINS + bin], conf);
            atomicAdd(&sb[2 * N_BINS + bin], acc);
        }

        #pragma unroll
        for (int c = 0; c < 4; ++c) v[c] = vn[c];
    }
    __syncthreads();

    // block-level flush + completion signal
    if (tid < NSLOTS) {
        atomicAdd(&gbins[tid], sb[tid]);
        __threadfence();           // make our sums visible before counter bump
    }
    __syncthreads();
    if (tid == 0) {
        unsigned prev = atomicAdd((unsigned*)(gbins + NSLOTS), 1u);
        sLast = (prev == gridDim.x - 1) ? 1u : 0u;
    }
    __syncthreads();

    if (sLast) {
        __threadfence();
        __shared__ float s_ece[N_BINS];
        if (tid < N_BINS) {
            // atomicAdd(p, 0.0f): coherent read past any stale cache
            float cnt   = atomicAdd(&gbins[tid], 0.0f);
            float sconf = atomicAdd(&gbins[N_BINS + tid], 0.0f);
            float sacc  = atomicAdd(&gbins[2 * N_BINS + tid], 0.0f);
            bool  ne    = cnt > 0.0f;
            float sc    = ne ? cnt : 1.0f;
            float avg_conf = sconf / sc;
            float avg_acc  = sacc / sc;
            float prop     = cnt * invN;
            s_ece[tid] = ne ? fabsf(avg_conf - avg_acc) * prop : 0.0f;
            out[1 + tid]          = ne ? avg_conf : ((float)tid + 0.5f) / (float)N_BINS;
            out[1 + N_BINS + tid] = ne ? avg_acc  : 0.0f;
        }
        __syncthreads();
        if (tid == 0) {
            float e = 0.0f;
            for (int j = 0; j < N_BINS; ++j) e += s_ece[j];
            out[0] = e;
        }
    }
}

extern "C" void kernel_launch(void* const* d_in, const int* in_sizes, int n_in,
                              void* d_out, int out_size, void* d_ws, size_t ws_size,
                              hipStream_t stream) {
    const float* logits = (const float*)d_in[0];
    const int*   labels = (const int*)d_in[1];
    int N = in_sizes[1];
    int C = in_sizes[0] / N;   // 1000

    float* gbins = (float*)d_ws;  // [45 sums][1 counter]
    (void)hipMemsetAsync(gbins, 0, (NSLOTS + 1) * sizeof(float), stream);

    const int blocks = 2048;  // 8192 waves, 32 rows/wave grid-stride (exact)
    ece_main<<<blocks, 256, 0, stream>>>(logits, labels, gbins, (float*)d_out,
                                         N, C, 1.0f / (float)N);
}

// Round 7
// 191.728 us; speedup vs baseline: 1.3945x; 1.3945x over previous
//
#include <hip/hip_runtime.h>
#include <math.h>

#define N_BINS 15

typedef float fvec4 __attribute__((ext_vector_type(4)));  // native clang vector:
// __builtin_nontemporal_load needs scalar/native-vector, not HIP_vector_type.

// One wave (64 lanes) per row, grid-stride over rows, software-prefetched,
// NONTEMPORAL logits loads (pure 1.05 GB stream, zero reuse -> don't retain
// in L2/L3; measured +7%, R5). Per-block bin sums in LDS; 45 global atomics
// per block at end. Measured-faster than:
//  - two-stage non-atomic partials (R3: +24us, single-reader reduction)
//  - fused last-block-done epilogue (R6: +78us, per-block __threadfence
//    L2-writeback disturbs the nt stream).
__global__ __launch_bounds__(256) void ece_main(const float* __restrict__ logits,
                                                const int* __restrict__ labels,
                                                float* __restrict__ gbins, // [3][N_BINS]
                                                int N, int C) {
    __shared__ float sb[3 * N_BINS];
    const int tid = threadIdx.x;
    if (tid < 3 * N_BINS) sb[tid] = 0.0f;
    __syncthreads();

    const int lane = tid & 63;
    const int wid  = tid >> 6;
    const int wavesPerBlock = blockDim.x >> 6;
    const int wavesTotal = gridDim.x * wavesPerBlock;
    const int C4 = C >> 2;  // 250 for C=1000

    int row = blockIdx.x * wavesPerBlock + wid;

    fvec4 v[4];
    const fvec4 ninf = (fvec4)(-INFINITY);
    if (row < N) {
        const fvec4* rp = (const fvec4*)(logits + (size_t)row * C);
        #pragma unroll
        for (int c = 0; c < 4; ++c) {
            int f4i = c * 64 + lane;
            v[c] = (f4i < C4) ? __builtin_nontemporal_load(&rp[f4i]) : ninf;
        }
    }

    for (; row < N; row += wavesTotal) {
        int lbl = labels[row];

        // prefetch next row while we reduce this one
        int nrow = row + wavesTotal;
        fvec4 vn[4];
        if (nrow < N) {
            const fvec4* np = (const fvec4*)(logits + (size_t)nrow * C);
            #pragma unroll
            for (int c = 0; c < 4; ++c) {
                int f4i = c * 64 + lane;
                vn[c] = (f4i < C4) ? __builtin_nontemporal_load(&np[f4i]) : ninf;
            }
        } else {
            #pragma unroll
            for (int c = 0; c < 4; ++c) vn[c] = ninf;
        }

        // per-lane max + first-occurrence argmax (ascending scan, strict >)
        float m = -INFINITY;
        int   mi = 0x7fffffff;
        #pragma unroll
        for (int c = 0; c < 4; ++c) {
            int base = (c * 64 + lane) * 4;
            #pragma unroll
            for (int j = 0; j < 4; ++j) {
                float e = v[c][j];
                if (e > m) { m = e; mi = base + j; }
            }
        }
        // wave reduce: max, tie-break to smallest index
        #pragma unroll
        for (int off = 1; off < 64; off <<= 1) {
            float om = __shfl_xor(m, off, 64);
            int   oi = __shfl_xor(mi, off, 64);
            if (om > m || (om == m && oi < mi)) { m = om; mi = oi; }
        }

        // sum of exp(x - max); -inf fill lanes contribute exp(-inf)=0
        float s = 0.0f;
        #pragma unroll
        for (int c = 0; c < 4; ++c) {
            #pragma unroll
            for (int j = 0; j < 4; ++j) s += __expf(v[c][j] - m);
        }
        #pragma unroll
        for (int off = 1; off < 64; off <<= 1) s += __shfl_xor(s, off, 64);

        if (lane == 0) {
            float conf = 1.0f / s;                        // exp(max-max)/Z = 1/Z
            int bin = (int)ceilf(conf * (float)N_BINS) - 1;
            bin = bin < 0 ? 0 : (bin > N_BINS - 1 ? N_BINS - 1 : bin);
            float acc = (mi == lbl) ? 1.0f : 0.0f;
            atomicAdd(&sb[bin], 1.0f);
            atomicAdd(&sb[N_BINS + bin], conf);
            atomicAdd(&sb[2 * N_BINS + bin], acc);
        }

        #pragma unroll
        for (int c = 0; c < 4; ++c) v[c] = vn[c];
    }
    __syncthreads();
    if (tid < 3 * N_BINS) atomicAdd(&gbins[tid], sb[tid]);
}

// Epilogue: 31 outputs = [ece, confs_binned[15], accs_binned[15]]
__global__ void ece_final(const float* __restrict__ gbins, float* __restrict__ out,
                          float invN) {
    __shared__ float s_ece[N_BINS];
    int i = threadIdx.x;
    if (i < N_BINS) {
        float cnt   = gbins[i];
        float sconf = gbins[N_BINS + i];
        float sacc  = gbins[2 * N_BINS + i];
        bool  ne    = cnt > 0.0f;
        float sc    = ne ? cnt : 1.0f;
        float avg_conf = sconf / sc;
        float avg_acc  = sacc / sc;
        float prop     = cnt * invN;
        s_ece[i] = ne ? fabsf(avg_conf - avg_acc) * prop : 0.0f;
        out[1 + i]          = ne ? avg_conf : ((float)i + 0.5f) / (float)N_BINS;
        out[1 + N_BINS + i] = ne ? avg_acc  : 0.0f;
    }
    __syncthreads();
    if (i == 0) {
        float e = 0.0f;
        for (int j = 0; j < N_BINS; ++j) e += s_ece[j];
        out[0] = e;
    }
}

extern "C" void kernel_launch(void* const* d_in, const int* in_sizes, int n_in,
                              void* d_out, int out_size, void* d_ws, size_t ws_size,
                              hipStream_t stream) {
    const float* logits = (const float*)d_in[0];
    const int*   labels = (const int*)d_in[1];
    int N = in_sizes[1];
    int C = in_sizes[0] / N;   // 1000

    float* gbins = (float*)d_ws;  // [3][N_BINS] accumulators
    (void)hipMemsetAsync(gbins, 0, 3 * N_BINS * sizeof(float), stream);

    const int blocks = 2048;  // 8192 waves, 32 rows/wave grid-stride (exact)
    ece_main<<<blocks, 256, 0, stream>>>(logits, labels, gbins, N, C);
    ece_final<<<1, 64, 0, stream>>>(gbins, (float*)d_out, 1.0f / (float)N);
}